// Round 4
// baseline (271.967 us; speedup 1.0000x reference)
//
#include <hip/hip_runtime.h>
#include <math.h>

#define BB 256
#define VV 4096
#define DD 64

typedef __attribute__((ext_vector_type(8))) _Float16 f16x8;
typedef __attribute__((ext_vector_type(4))) float f32x4;

// ---------------------------------------------------------------------------
// Kernel 1: one block (1024 threads, 16 waves) per a.
// wave = rg*? : rg = wave>>2 owns v-rows [1024*rg, 1024*rg+1024),
//              cg = wave&3 owns b-cols  [64*cg, 64*cg+64).
// lan fragments (fp16) in regs (32 VGPR); F loaded straight from global in
// A-fragment order, cvt in regs, 2-deep prefetch. No LDS / barriers in loop.
// The 4 colgroup waves of one rowgroup re-read the same F rows -> L1 hits.
// Output transposed: max0T[a*256+b], max1T[a*256+b].
// ---------------------------------------------------------------------------
__global__ __launch_bounds__(1024, 4) void topk_sim_kernel(
    const float* __restrict__ F, const float* __restrict__ lan,
    float* __restrict__ max0T, float* __restrict__ max1T)
{
  __shared__ float mrg[16][64][2];   // 8 KB cross-wave merge buffer
  const int t = threadIdx.x;
  const int a = blockIdx.x;
  const int wave = t >> 6;
  const int lane = t & 63;
  const int cl = lane & 15;      // A-row / B-col / C-col within 16x16 tile
  const int o  = lane >> 4;      // k-octet group
  const int rg = wave >> 2;      // row group
  const int cg = wave & 3;       // col group

  // ---- B fragments: 4 col-tiles x 2 ksubs, fp16, direct from global ----
  f16x8 bf[4][2];
#pragma unroll
  for (int ct = 0; ct < 4; ++ct) {
    const float* p = lan + (cg * 64 + ct * 16 + cl) * DD + o * 8;
#pragma unroll
    for (int s = 0; s < 2; ++s) {
      f16x8 v;
#pragma unroll
      for (int e = 0; e < 8; ++e) v[e] = (_Float16)p[s * 32 + e];
      bf[ct][s] = v;
    }
  }

  float m0[4], m1[4];
#pragma unroll
  for (int ct = 0; ct < 4; ++ct) { m0[ct] = -INFINITY; m1[ct] = -INFINITY; }

  // per-lane base: row = 1024*rg + chunk*16 + cl, k-octet o (both ksubs)
  const float* Fa = F + (size_t)a * VV * DD + (size_t)rg * 1024 * DD
                    + cl * DD + o * 8;

  // ---- 2-deep prefetch pipeline over 64 chunks of 16 rows ----
  float4 c0[2], c1[2], c2[2], c3[2];
#pragma unroll
  for (int i = 0; i < 2; ++i) {
    const float* p = Fa + i * 16 * DD;
    c0[i] = *(const float4*)(p);      c1[i] = *(const float4*)(p + 4);
    c2[i] = *(const float4*)(p + 32); c3[i] = *(const float4*)(p + 36);
  }

#pragma unroll 1
  for (int ch = 0; ch < 64; ++ch) {
    const int pb = ch & 1;
    // fp32 -> fp16 A fragments (consumes buffer pb)
    f16x8 a0, a1;
    a0[0] = (_Float16)c0[pb].x; a0[1] = (_Float16)c0[pb].y;
    a0[2] = (_Float16)c0[pb].z; a0[3] = (_Float16)c0[pb].w;
    a0[4] = (_Float16)c1[pb].x; a0[5] = (_Float16)c1[pb].y;
    a0[6] = (_Float16)c1[pb].z; a0[7] = (_Float16)c1[pb].w;
    a1[0] = (_Float16)c2[pb].x; a1[1] = (_Float16)c2[pb].y;
    a1[2] = (_Float16)c2[pb].z; a1[3] = (_Float16)c2[pb].w;
    a1[4] = (_Float16)c3[pb].x; a1[5] = (_Float16)c3[pb].y;
    a1[6] = (_Float16)c3[pb].z; a1[7] = (_Float16)c3[pb].w;

    // refill buffer pb with chunk ch+2 (lands ~2 chunks of compute later)
    if (ch + 2 < 64) {
      const float* p = Fa + (ch + 2) * 16 * DD;
      c0[pb] = *(const float4*)(p);      c1[pb] = *(const float4*)(p + 4);
      c2[pb] = *(const float4*)(p + 32); c3[pb] = *(const float4*)(p + 36);
    }

#pragma unroll
    for (int ct = 0; ct < 4; ++ct) {
      f32x4 acc = {0.f, 0.f, 0.f, 0.f};
      acc = __builtin_amdgcn_mfma_f32_16x16x32_f16(a0, bf[ct][0], acc, 0, 0, 0);
      acc = __builtin_amdgcn_mfma_f32_16x16x32_f16(a1, bf[ct][1], acc, 0, 0, 0);
      // top-2 of the 4 accum values (4 rows, same column)
      float h1 = fmaxf(acc[0], acc[1]), q1 = fminf(acc[0], acc[1]);
      float h2 = fmaxf(acc[2], acc[3]), q2 = fminf(acc[2], acc[3]);
      float M0 = fmaxf(h1, h2);
      float M1 = fmaxf(fminf(h1, h2), fmaxf(q1, q2));
      // merge into running top-2
      float old0 = m0[ct];
      m0[ct] = fmaxf(old0, M0);
      m1[ct] = fmaxf(m1[ct], fmaxf(fminf(old0, M0), M1));
    }
  }

  // ---- merge across the 4 k-octet row-groups within the wave ----
#pragma unroll
  for (int ct = 0; ct < 4; ++ct) {
#pragma unroll
    for (int off = 16; off <= 32; off <<= 1) {
      float p0 = __shfl_xor(m0[ct], off);
      float p1 = __shfl_xor(m1[ct], off);
      float n1 = fmaxf(fminf(m0[ct], p0), fmaxf(m1[ct], p1));
      m0[ct] = fmaxf(m0[ct], p0);
      m1[ct] = n1;
    }
    if (lane < 16) {
      mrg[wave][ct * 16 + lane][0] = m0[ct];
      mrg[wave][ct * 16 + lane][1] = m1[ct];
    }
  }
  __syncthreads();

  // ---- merge the 4 rowgroup waves of each colgroup; store ----
  if (t < BB) {
    const int cg2 = t >> 6, lc = t & 63;   // global col == t
    float M0 = -INFINITY, M1 = -INFINITY;
#pragma unroll
    for (int r = 0; r < 4; ++r) {
      const int w = cg2 + 4 * r;
      float a0 = mrg[w][lc][0], a1 = mrg[w][lc][1];
      float n1 = fmaxf(fminf(M0, a0), fmaxf(M1, a1));
      M0 = fmaxf(M0, a0);
      M1 = n1;
    }
    max0T[a * BB + t] = M0;
    max1T[a * BB + t] = M1;
  }
}

// ---------------------------------------------------------------------------
// Kernel 2: per row b, LSE over 511 logits, loss_b = LSE - diag.
// ---------------------------------------------------------------------------
__global__ __launch_bounds__(256) void lse_kernel(
    const float* __restrict__ max0T, const float* __restrict__ max1T,
    float* __restrict__ lossb)
{
  __shared__ float red[256];
  __shared__ float diag;
  const int b = blockIdx.x;
  const int t = threadIdx.x;     // t = a
  float x0 = max0T[t * BB + b];
  float x1 = (t == b) ? -INFINITY : max1T[t * BB + b];
  if (t == b) diag = x0;
  red[t] = fmaxf(x0, x1);
  __syncthreads();
  for (int s = 128; s > 0; s >>= 1) {
    if (t < s) red[t] = fmaxf(red[t], red[t + s]);
    __syncthreads();
  }
  float M = red[0];
  __syncthreads();
  float e = expf(x0 - M) + ((t == b) ? 0.0f : expf(x1 - M));
  red[t] = e;
  __syncthreads();
  for (int s = 128; s > 0; s >>= 1) {
    if (t < s) red[t] = red[t] + red[t + s];
    __syncthreads();
  }
  if (t == 0) lossb[b] = logf(red[0]) + M - diag;
}

__global__ __launch_bounds__(256) void mean_kernel(
    const float* __restrict__ lossb, float* __restrict__ out)
{
  __shared__ float red[256];
  const int t = threadIdx.x;
  red[t] = lossb[t];
  __syncthreads();
  for (int s = 128; s > 0; s >>= 1) {
    if (t < s) red[t] += red[t + s];
    __syncthreads();
  }
  if (t == 0) out[0] = red[0] * (1.0f / 256.0f);
}

extern "C" void kernel_launch(void* const* d_in, const int* in_sizes, int n_in,
                              void* d_out, int out_size, void* d_ws, size_t ws_size,
                              hipStream_t stream) {
  const float* F   = (const float*)d_in[0];   // fusion_fs [256,4096,64] fp32
  const float* lan = (const float*)d_in[1];   // lan_fs    [256,1,64]   fp32
  float* ws = (float*)d_ws;
  float* max0T = ws;                // [256*256]
  float* max1T = ws + 65536;        // [256*256]
  float* lossb = ws + 131072;       // [256]

  topk_sim_kernel<<<256, 1024, 0, stream>>>(F, lan, max0T, max1T);
  lse_kernel<<<256, 256, 0, stream>>>(max0T, max1T, lossb);
  mean_kernel<<<1, 256, 0, stream>>>(lossb, (float*)d_out);
}

// Round 5
// 132.310 us; speedup vs baseline: 2.0555x; 2.0555x over previous
//
#include <hip/hip_runtime.h>
#include <math.h>

#define BB 256
#define VV 4096
#define DD 64

typedef __attribute__((ext_vector_type(8))) _Float16 f16x8;
typedef __attribute__((ext_vector_type(4))) float f32x4;

// ---------------------------------------------------------------------------
// Kernel 1: one block (1024 threads, 16 waves) per a.
// rg = wave>>2 owns v-rows [1024*rg, 1024*rg+1024),
// cg = wave&3  owns b-cols [64*cg, 64*cg+64).
// lan fragments (fp16) in regs (32 VGPR); F loaded from global in A-fragment
// order, cvt in regs. 2-deep prefetch with STATICALLY-NAMED buffers (rule #20:
// runtime-indexed reg arrays go to scratch — round-4 lesson). No LDS/barriers
// in the main loop. Output transposed: max0T[a*256+b], max1T[a*256+b].
// ---------------------------------------------------------------------------
__global__ __launch_bounds__(1024, 4) void topk_sim_kernel(
    const float* __restrict__ F, const float* __restrict__ lan,
    float* __restrict__ max0T, float* __restrict__ max1T)
{
  __shared__ float mrg[16][64][2];   // 8 KB cross-wave merge buffer
  const int t = threadIdx.x;
  const int a = blockIdx.x;
  const int wave = t >> 6;
  const int lane = t & 63;
  const int cl = lane & 15;      // A-row / B-col / C-col within 16x16 tile
  const int o  = lane >> 4;      // k-octet group
  const int rg = wave >> 2;      // row group
  const int cg = wave & 3;       // col group

  // ---- B fragments: 4 col-tiles x 2 ksubs, fp16, direct from global ----
  f16x8 bf[4][2];
#pragma unroll
  for (int ct = 0; ct < 4; ++ct) {
    const float* p = lan + (cg * 64 + ct * 16 + cl) * DD + o * 8;
#pragma unroll
    for (int s = 0; s < 2; ++s) {
      f16x8 v;
#pragma unroll
      for (int e = 0; e < 8; ++e) v[e] = (_Float16)p[s * 32 + e];
      bf[ct][s] = v;
    }
  }

  float m0[4], m1[4];
#pragma unroll
  for (int ct = 0; ct < 4; ++ct) { m0[ct] = -INFINITY; m1[ct] = -INFINITY; }

  // per-lane base: row = 1024*rg + chunk*16 + cl, k-octet o (both ksubs)
  const float* Fa = F + (size_t)a * VV * DD + (size_t)rg * 1024 * DD
                    + cl * DD + o * 8;

  // ---- statically-named 2-deep prefetch: set A = even chunks, B = odd ----
  float4 A0, A1, A2, A3, B0, B1, B2, B3;
  {
    const float* p = Fa;
    A0 = *(const float4*)(p);      A1 = *(const float4*)(p + 4);
    A2 = *(const float4*)(p + 32); A3 = *(const float4*)(p + 36);
    p = Fa + 16 * DD;
    B0 = *(const float4*)(p);      B1 = *(const float4*)(p + 4);
    B2 = *(const float4*)(p + 32); B3 = *(const float4*)(p + 36);
  }

#define CVT_FRAGS(x0, x1, x2, x3)                                   \
    a0[0] = (_Float16)x0.x; a0[1] = (_Float16)x0.y;                 \
    a0[2] = (_Float16)x0.z; a0[3] = (_Float16)x0.w;                 \
    a0[4] = (_Float16)x1.x; a0[5] = (_Float16)x1.y;                 \
    a0[6] = (_Float16)x1.z; a0[7] = (_Float16)x1.w;                 \
    a1[0] = (_Float16)x2.x; a1[1] = (_Float16)x2.y;                 \
    a1[2] = (_Float16)x2.z; a1[3] = (_Float16)x2.w;                 \
    a1[4] = (_Float16)x3.x; a1[5] = (_Float16)x3.y;                 \
    a1[6] = (_Float16)x3.z; a1[7] = (_Float16)x3.w;

#define MFMA_FOLD()                                                 \
    _Pragma("unroll")                                               \
    for (int ct = 0; ct < 4; ++ct) {                                \
      f32x4 acc = {0.f, 0.f, 0.f, 0.f};                             \
      acc = __builtin_amdgcn_mfma_f32_16x16x32_f16(a0, bf[ct][0], acc, 0, 0, 0); \
      acc = __builtin_amdgcn_mfma_f32_16x16x32_f16(a1, bf[ct][1], acc, 0, 0, 0); \
      float h1 = fmaxf(acc[0], acc[1]), q1 = fminf(acc[0], acc[1]); \
      float h2 = fmaxf(acc[2], acc[3]), q2 = fminf(acc[2], acc[3]); \
      float M0 = fmaxf(h1, h2);                                     \
      float M1 = fmaxf(fminf(h1, h2), fmaxf(q1, q2));               \
      float old0 = m0[ct];                                          \
      m0[ct] = fmaxf(old0, M0);                                     \
      m1[ct] = fmaxf(m1[ct], fmaxf(fminf(old0, M0), M1));           \
    }

#pragma unroll 1
  for (int q = 0; q < 32; ++q) {
    const int ch = 2 * q;
    // ---- chunk ch (buffer A) ----
    {
      f16x8 a0, a1;
      CVT_FRAGS(A0, A1, A2, A3)
      if (ch + 2 < 64) {
        const float* p = Fa + (size_t)(ch + 2) * 16 * DD;
        A0 = *(const float4*)(p);      A1 = *(const float4*)(p + 4);
        A2 = *(const float4*)(p + 32); A3 = *(const float4*)(p + 36);
      }
      MFMA_FOLD()
    }
    // ---- chunk ch+1 (buffer B) ----
    {
      f16x8 a0, a1;
      CVT_FRAGS(B0, B1, B2, B3)
      if (ch + 3 < 64) {
        const float* p = Fa + (size_t)(ch + 3) * 16 * DD;
        B0 = *(const float4*)(p);      B1 = *(const float4*)(p + 4);
        B2 = *(const float4*)(p + 32); B3 = *(const float4*)(p + 36);
      }
      MFMA_FOLD()
    }
  }
#undef CVT_FRAGS
#undef MFMA_FOLD

  // ---- merge across the 4 k-octet row-groups within the wave ----
#pragma unroll
  for (int ct = 0; ct < 4; ++ct) {
#pragma unroll
    for (int off = 16; off <= 32; off <<= 1) {
      float p0 = __shfl_xor(m0[ct], off);
      float p1 = __shfl_xor(m1[ct], off);
      float n1 = fmaxf(fminf(m0[ct], p0), fmaxf(m1[ct], p1));
      m0[ct] = fmaxf(m0[ct], p0);
      m1[ct] = n1;
    }
    if (lane < 16) {
      mrg[wave][ct * 16 + lane][0] = m0[ct];
      mrg[wave][ct * 16 + lane][1] = m1[ct];
    }
  }
  __syncthreads();

  // ---- merge the 4 rowgroup waves of each colgroup; store ----
  if (t < BB) {
    const int cg2 = t >> 6, lc = t & 63;   // global col == t
    float M0 = -INFINITY, M1 = -INFINITY;
#pragma unroll
    for (int r = 0; r < 4; ++r) {
      const int w = cg2 + 4 * r;
      float a0 = mrg[w][lc][0], a1 = mrg[w][lc][1];
      float n1 = fmaxf(fminf(M0, a0), fmaxf(M1, a1));
      M0 = fmaxf(M0, a0);
      M1 = n1;
    }
    max0T[a * BB + t] = M0;
    max1T[a * BB + t] = M1;
  }
}

// ---------------------------------------------------------------------------
// Kernel 2: per row b, LSE over 511 logits, loss_b = LSE - diag.
// ---------------------------------------------------------------------------
__global__ __launch_bounds__(256) void lse_kernel(
    const float* __restrict__ max0T, const float* __restrict__ max1T,
    float* __restrict__ lossb)
{
  __shared__ float red[256];
  __shared__ float diag;
  const int b = blockIdx.x;
  const int t = threadIdx.x;     // t = a
  float x0 = max0T[t * BB + b];
  float x1 = (t == b) ? -INFINITY : max1T[t * BB + b];
  if (t == b) diag = x0;
  red[t] = fmaxf(x0, x1);
  __syncthreads();
  for (int s = 128; s > 0; s >>= 1) {
    if (t < s) red[t] = fmaxf(red[t], red[t + s]);
    __syncthreads();
  }
  float M = red[0];
  __syncthreads();
  float e = expf(x0 - M) + ((t == b) ? 0.0f : expf(x1 - M));
  red[t] = e;
  __syncthreads();
  for (int s = 128; s > 0; s >>= 1) {
    if (t < s) red[t] = red[t] + red[t + s];
    __syncthreads();
  }
  if (t == 0) lossb[b] = logf(red[0]) + M - diag;
}

__global__ __launch_bounds__(256) void mean_kernel(
    const float* __restrict__ lossb, float* __restrict__ out)
{
  __shared__ float red[256];
  const int t = threadIdx.x;
  red[t] = lossb[t];
  __syncthreads();
  for (int s = 128; s > 0; s >>= 1) {
    if (t < s) red[t] += red[t + s];
    __syncthreads();
  }
  if (t == 0) out[0] = red[0] * (1.0f / 256.0f);
}

extern "C" void kernel_launch(void* const* d_in, const int* in_sizes, int n_in,
                              void* d_out, int out_size, void* d_ws, size_t ws_size,
                              hipStream_t stream) {
  const float* F   = (const float*)d_in[0];   // fusion_fs [256,4096,64] fp32
  const float* lan = (const float*)d_in[1];   // lan_fs    [256,1,64]   fp32
  float* ws = (float*)d_ws;
  float* max0T = ws;                // [256*256]
  float* max1T = ws + 65536;        // [256*256]
  float* lossb = ws + 131072;       // [256]

  topk_sim_kernel<<<256, 1024, 0, stream>>>(F, lan, max0T, max1T);
  lse_kernel<<<256, 256, 0, stream>>>(max0T, max1T, lossb);
  mean_kernel<<<1, 256, 0, stream>>>(lossb, (float*)d_out);
}